// Round 19
// baseline (138.768 us; speedup 1.0000x reference)
//
#include <hip/hip_runtime.h>

#define NCOMM 512
#define DIM   128
#define ALPHA 0.25f
#define PEPS  1e-6f
#define BIGF  1e30f
#define TILE_C 16
#define NT    (NCOMM / TILE_C)   // 32 tiles, 64 half-K substages

typedef __attribute__((ext_vector_type(8))) _Float16 f16x8;
typedef __attribute__((ext_vector_type(4))) float f32x4;

#define GLOAD_LDS16(g, l) __builtin_amdgcn_global_load_lds( \
    (const __attribute__((address_space(1))) void*)(g), \
    (__attribute__((address_space(3))) void*)(l), 16, 0, 0)

// ---------------- prep: comm scatter + histogram (inv eliminated) ----------------
// inv[cbl[i]] = i  =>  comm[cbl[i]] = cbl[N+i] directly; idx0 == identity (algebra).

__global__ void k_prep(const int* __restrict__ cbl, int* __restrict__ comm,
                       int* __restrict__ counts, int N) {
    __shared__ int h[NCOMM];
    int t = threadIdx.x;
    h[t] = 0; h[t + 256] = 0;
    __syncthreads();
    int i = blockIdx.x * 256 + t;
    if (i < N) {
        int p = cbl[i];
        int c = cbl[N + i];
        comm[p] = c;
        atomicAdd(&h[c], 1);
    }
    __syncthreads();
    int v = h[t];        if (v) atomicAdd(&counts[t], v);
    v = h[t + 256];      if (v) atomicAdd(&counts[t + 256], v);
}

__global__ void k_scan(const int* __restrict__ counts, int* __restrict__ offsets,
                       int* __restrict__ cursor, float* __restrict__ countf) {
    __shared__ int sc[NCOMM];
    int t = threadIdx.x;
    int v0 = counts[t];
    sc[t] = v0;
    __syncthreads();
    for (int off = 1; off < NCOMM; off <<= 1) {
        int v = (t >= off) ? sc[t - off] : 0;
        __syncthreads();
        sc[t] += v;
        __syncthreads();
    }
    int excl = sc[t] - v0;
    offsets[t] = excl;
    cursor[t]  = excl;
    countf[t]  = (float)v0;
}

// 1024 elements per block: LDS histogram + one range-reservation atomic per present comm
__global__ void k_sort(const int* __restrict__ comm, int* __restrict__ cursor,
                       int* __restrict__ sorted, int N) {
    __shared__ int h[NCOMM], hb[NCOMM];
    int t = threadIdx.x;
    h[t] = 0; h[t + 256] = 0;
    __syncthreads();
    int j0 = blockIdx.x * 1024 + t;
    int cs[4];
    #pragma unroll
    for (int q = 0; q < 4; ++q) {
        int j = j0 + q * 256;
        cs[q] = (j < N) ? comm[j] : -1;
        if (cs[q] >= 0) atomicAdd(&h[cs[q]], 1);
    }
    __syncthreads();
    int v = h[t];        if (v) hb[t] = atomicAdd(&cursor[t], v);
    v = h[t + 256];      if (v) hb[t + 256] = atomicAdd(&cursor[t + 256], v);
    __syncthreads();
    #pragma unroll
    for (int q = 0; q < 4; ++q) {
        int j = j0 + q * 256;
        if (cs[q] >= 0) {
            int p = atomicAdd(&hb[cs[q]], 1);
            sorted[p] = j;
        }
    }
}

// ---------------- per-community stats: float4 gather, single pass ----------------
// var = (sumsq - cnt*m^2)/(cnt-1): benign cancellation (x~N(0,1), rel err ~1e-6)
// Emits community means as single fp16 (distance error ~5e-5, see k_main note).
// Gather unrolled x4 -> 4 loads in flight per thread.

__global__ void __launch_bounds__(256) k_stats(
        const float* __restrict__ NF,
        const int* __restrict__ sorted, const int* __restrict__ offsets,
        const int* __restrict__ counts,
        float* __restrict__ comm_sum,
        _Float16* __restrict__ CMh,
        float* __restrict__ c2, float* __restrict__ accum) {
    __shared__ int ridx[512];
    __shared__ float4 bufS[256], bufQ[256];
    int c = blockIdx.x, t = threadIdx.x;
    int d4 = t & 31, r = t >> 5;                 // 32 dim-quads x 8 row slots
    int cnt = counts[c], base = offsets[c];
    const float4* NF4 = (const float4*)NF;

    float4 s4 = make_float4(0.f, 0.f, 0.f, 0.f);
    float4 q4 = make_float4(0.f, 0.f, 0.f, 0.f);
    for (int chunk = 0; chunk < cnt; chunk += 512) {
        int m = min(cnt - chunk, 512);
        for (int i = t; i < m; i += 256) ridx[i] = sorted[base + chunk + i];
        __syncthreads();
        int i = r;
        for (; i + 24 < m; i += 32) {
            int a0 = ridx[i], a1 = ridx[i + 8], a2 = ridx[i + 16], a3 = ridx[i + 24];
            float4 v0 = NF4[(size_t)a0 * 32 + d4];
            float4 v1 = NF4[(size_t)a1 * 32 + d4];
            float4 v2 = NF4[(size_t)a2 * 32 + d4];
            float4 v3 = NF4[(size_t)a3 * 32 + d4];
            s4.x += v0.x; s4.y += v0.y; s4.z += v0.z; s4.w += v0.w;
            q4.x = fmaf(v0.x, v0.x, q4.x); q4.y = fmaf(v0.y, v0.y, q4.y);
            q4.z = fmaf(v0.z, v0.z, q4.z); q4.w = fmaf(v0.w, v0.w, q4.w);
            s4.x += v1.x; s4.y += v1.y; s4.z += v1.z; s4.w += v1.w;
            q4.x = fmaf(v1.x, v1.x, q4.x); q4.y = fmaf(v1.y, v1.y, q4.y);
            q4.z = fmaf(v1.z, v1.z, q4.z); q4.w = fmaf(v1.w, v1.w, q4.w);
            s4.x += v2.x; s4.y += v2.y; s4.z += v2.z; s4.w += v2.w;
            q4.x = fmaf(v2.x, v2.x, q4.x); q4.y = fmaf(v2.y, v2.y, q4.y);
            q4.z = fmaf(v2.z, v2.z, q4.z); q4.w = fmaf(v2.w, v2.w, q4.w);
            s4.x += v3.x; s4.y += v3.y; s4.z += v3.z; s4.w += v3.w;
            q4.x = fmaf(v3.x, v3.x, q4.x); q4.y = fmaf(v3.y, v3.y, q4.y);
            q4.z = fmaf(v3.z, v3.z, q4.z); q4.w = fmaf(v3.w, v3.w, q4.w);
        }
        for (; i < m; i += 8) {
            float4 v = NF4[(size_t)ridx[i] * 32 + d4];
            s4.x += v.x; s4.y += v.y; s4.z += v.z; s4.w += v.w;
            q4.x = fmaf(v.x, v.x, q4.x); q4.y = fmaf(v.y, v.y, q4.y);
            q4.z = fmaf(v.z, v.z, q4.z); q4.w = fmaf(v.w, v.w, q4.w);
        }
        __syncthreads();
    }
    bufS[t] = s4; bufQ[t] = q4;
    __syncthreads();
    if (t < 128) {
        float4 a = bufS[t], b = bufS[t + 128];
        a.x += b.x; a.y += b.y; a.z += b.z; a.w += b.w; bufS[t] = a;
        float4 e = bufQ[t], f = bufQ[t + 128];
        e.x += f.x; e.y += f.y; e.z += f.z; e.w += f.w; bufQ[t] = e;
    }
    __syncthreads();
    if (t < 64) {
        float4 a = bufS[t], b = bufS[t + 64];
        a.x += b.x; a.y += b.y; a.z += b.z; a.w += b.w; bufS[t] = a;
        float4 e = bufQ[t], f = bufQ[t + 64];
        e.x += f.x; e.y += f.y; e.z += f.z; e.w += f.w; bufQ[t] = e;
    }
    __syncthreads();
    if (t < 32) {
        float4 a = bufS[t], b = bufS[t + 32];
        a.x += b.x; a.y += b.y; a.z += b.z; a.w += b.w;
        float4 e = bufQ[t], f = bufQ[t + 32];
        e.x += f.x; e.y += f.y; e.z += f.z; e.w += f.w;
        float sarr[4] = {a.x, a.y, a.z, a.w};
        float qarr[4] = {e.x, e.y, e.z, e.w};
        float cf = (float)cnt;
        float mm = 0.f, ee = 0.f;
        #pragma unroll
        for (int k = 0; k < 4; ++k) {
            int d = t * 4 + k;
            float s = sarr[k];
            comm_sum[c * DIM + d] = s;
            float m = (cnt > 0) ? s / cf : 0.f;
            CMh[c * DIM + d] = (_Float16)m;
            float varn = fmaxf(fmaf(-cf * m, m, qarr[k]), 0.f);
            float stdv = sqrtf(varn / fmaxf(cf - 1.f, 1.f));
            float er = stdv - 1.f;
            mm = fmaf(m, m, mm);
            ee = fmaf(er, er, ee);
        }
        #pragma unroll
        for (int msk = 1; msk < 32; msk <<= 1) {
            mm += __shfl_xor(mm, msk);
            ee += __shfl_xor(ee, msk);
        }
        if (t == 0) {
            c2[c] = mm;
            atomicAdd(&accum[2], ee);
        }
    }
}

// ---------------- heavy kernel: MFMA distances + triplet terms ----------------
// M=128 rows per wave, ONE wave (64 threads) per block, grid 782 <= 1024 SIMDs:
// single generation, each wave runs solo on its SIMD -- per-SIMD substage count
// drops ~96 -> 64 and every substage's fixed overhead now feeds 16 MFMAs + a
// 32-row epilogue. Same depth-3 vmcnt(6) schedule verbatim (tails 6/4/2/0).
// launch_bounds(64,1): up to 512 VGPR (live state ~310, no spill expected).
// ~3 independent 1-wave blocks co-reside per CU -> staging/compute overlap
// across blocks with zero barrier coupling.

__global__ void __launch_bounds__(64, 1) k_main(
        const float* __restrict__ NF,
        const _Float16* __restrict__ CMh,
        const float* __restrict__ comm_sum,
        const float* __restrict__ c2g,
        const float* __restrict__ countf,
        const int* __restrict__ comm,
        float* __restrict__ accum, int N) {
    __shared__ _Float16 Bst[4][TILE_C * 64];  // 2 KB each = 8 KB
    __shared__ float c2s[NCOMM];
    __shared__ int   comms[128];
    __shared__ float x2sh[128];    // holds -x^2/2
    __shared__ float sums[128], mins[128];

    int tid = threadIdx.x;         // 0..63 (one wave)
    int lr = tid & 15;    // A row within 16-frag / B (comm) col
    int lk = tid >> 4;    // k-group
    int n0 = blockIdx.x * 128;

    // per-lane pre-swizzled source offset within a half-tile (16 comms x 64 dims):
    // chunk p = i*64+l -> row = i*8+(l>>3), cp = l&7, swz = cp^(row&7)
    int off0 = ((tid >> 3) << 7) + (((tid & 7) ^ ((tid >> 3) & 7)) << 3);
    const _Float16* gsrc = CMh + off0;
    // substage ss: tile = ss>>1 (16 comms), khalf = ss&1 (64 dims)
    auto stage = [&](int ss, int b) {
        const _Float16* g = gsrc + (size_t)(ss >> 1) * 2048 + (ss & 1) * 64;
        _Float16* lh = &Bst[b][0];
        GLOAD_LDS16(g,        lh);
        GLOAD_LDS16(g + 1024, lh + 512);
    };
    stage(0, 0); stage(1, 1); stage(2, 2);   // depth-3 prologue, lands during A conv

    #pragma unroll
    for (int q = 0; q < 8; ++q) c2s[q * 64 + tid] = c2g[q * 64 + tid];
    {
        int gn = n0 + tid;
        comms[tid] = (gn < N) ? comm[gn] : -1;
        gn = n0 + 64 + tid;
        comms[64 + tid] = (gn < N) ? comm[gn] : -1;
    }

    // ---- A fragments (rows n0 + mf*16 + lr), single fp16 + exact fp32 x2
    f16x8 ah[8][4];
    #pragma unroll
    for (int mf = 0; mf < 8; ++mf) {
        int n = n0 + mf * 16 + lr;
        const float4* src = (const float4*)NF + (size_t)n * 32 + lk * 2;
        float p2 = 0.f;
        #pragma unroll
        for (int ks = 0; ks < 4; ++ks) {
            float4 v0 = make_float4(0.f, 0.f, 0.f, 0.f), v1 = v0;
            if (n < N) { v0 = src[ks * 8]; v1 = src[ks * 8 + 1]; }
            float fr[8] = {v0.x, v0.y, v0.z, v0.w, v1.x, v1.y, v1.z, v1.w};
            f16x8 hh;
            #pragma unroll
            for (int t = 0; t < 8; ++t) {
                hh[t] = (_Float16)fr[t];
                p2 = fmaf(fr[t], fr[t], p2);
            }
            ah[mf][ks] = hh;
        }
        p2 += __shfl_xor(p2, 16);
        p2 += __shfl_xor(p2, 32);
        if (lk == 0) x2sh[mf * 16 + lr] = -0.5f * p2;
    }
    __syncthreads();   // drains stage(0..2) + publishes c2s/comms/x2sh

    // per-lane per-row state (C layout: row = lk*4 + j, col = lr)
    f32x4 x2v[8];
    int cnv[8][4];
    float sumv[8][4], minv[8][4];
    #pragma unroll
    for (int mf = 0; mf < 8; ++mf) {
        x2v[mf] = *(const f32x4*)&x2sh[mf * 16 + lk * 4];
        #pragma unroll
        for (int j = 0; j < 4; ++j) {
            cnv[mf][j] = comms[mf * 16 + lk * 4 + j];
            sumv[mf][j] = 0.f; minv[mf][j] = BIGF;
        }
    }

    for (int tt = 0; tt < NT; ++tt) {
        f32x4 acc[8];
        // ---- substage kh=0 (ss = 2tt): acc init
        {
            int ssn = 2 * tt + 3;
            if (ssn < 64) stage(ssn, ssn & 3);
            if (tt <= 30) { asm volatile("s_waitcnt vmcnt(6)" ::: "memory"); }
            else          { asm volatile("s_waitcnt vmcnt(2)" ::: "memory"); }
            const _Float16* bp = &Bst[(2 * tt) & 3][0];
            #pragma unroll
            for (int mf = 0; mf < 8; ++mf) acc[mf] = x2v[mf];
            #pragma unroll
            for (int ks2 = 0; ks2 < 2; ++ks2) {
                int ch = (ks2 * 4 + lk) ^ (lr & 7);
                f16x8 b = *(const f16x8*)&bp[(size_t)(lr * 64 + ch * 8)];
                #pragma unroll
                for (int mf = 0; mf < 8; ++mf)
                    acc[mf] = __builtin_amdgcn_mfma_f32_16x16x32_f16(ah[mf][ks2], b, acc[mf], 0, 0, 0);
            }
        }
        // ---- substage kh=1 (ss = 2tt+1): accumulate + epilogue
        {
            int ssn = 2 * tt + 4;
            if (ssn < 64) stage(ssn, ssn & 3);
            if (tt <= 29)      { asm volatile("s_waitcnt vmcnt(6)" ::: "memory"); }
            else if (tt == 30) { asm volatile("s_waitcnt vmcnt(4)" ::: "memory"); }
            else               { asm volatile("s_waitcnt vmcnt(0)" ::: "memory"); }
            const _Float16* bp = &Bst[(2 * tt + 1) & 3][0];
            #pragma unroll
            for (int ks2 = 0; ks2 < 2; ++ks2) {
                int ch = (ks2 * 4 + lk) ^ (lr & 7);
                f16x8 b = *(const f16x8*)&bp[(size_t)(lr * 64 + ch * 8)];
                #pragma unroll
                for (int mf = 0; mf < 8; ++mf)
                    acc[mf] = __builtin_amdgcn_mfma_f32_16x16x32_f16(ah[mf][2 + ks2], b, acc[mf], 0, 0, 0);
            }
            int ccol = tt * TILE_C + lr;
            float c2v = c2s[ccol];
            #pragma unroll
            for (int mf = 0; mf < 8; ++mf)
                #pragma unroll
                for (int j = 0; j < 4; ++j) {
                    // acc = dot - x^2/2  ->  d^2 = c^2 - 2*acc
                    float d2 = fmaf(-2.f, acc[mf][j], c2v);
                    float da = __builtin_amdgcn_sqrtf(fmaxf(d2, 0.f));
                    sumv[mf][j] += da;
                    minv[mf][j] = fminf(minv[mf][j], (cnv[mf][j] == ccol) ? BIGF : da);
                }
        }
    }

    // reduce sum/min across the 16 lr lanes sharing each node row
    #pragma unroll
    for (int mf = 0; mf < 8; ++mf)
        #pragma unroll
        for (int j = 0; j < 4; ++j) {
            float sv = sumv[mf][j], mv = minv[mf][j];
            #pragma unroll
            for (int msk = 1; msk < 16; msk <<= 1) {
                sv += __shfl_xor(sv, msk);
                mv = fminf(mv, __shfl_xor(mv, msk));
            }
            if (lr == 0) {
                int idx = mf * 16 + lk * 4 + j;
                sums[idx] = sv; mins[idx] = mv;
            }
        }
    __syncthreads();

    // LOO positive distance + own distance + triplet terms (2 nodes per thread)
    float tmean = 0.f, tminv = 0.f;
    for (int rr = 0; rr < 2; ++rr) {
        int ln = rr * 64 + tid;
        int n = n0 + ln;
        if (n < N) {
            int cnode = comms[ln];
            float cf  = countf[cnode];
            float cm1 = fmaxf(cf - 1.f, 1.f);
            float rs  = 1.f / cm1;
            bool single = (cf == 1.f);
            const float4* srow = (const float4*)NF + (size_t)n * 32;
            const float4* csum = (const float4*)(comm_sum + (size_t)cnode * DIM);
            float q = 0.f, dot = 0.f;
            #pragma unroll 8
            for (int m = 0; m < 32; ++m) {
                float4 sv = srow[m];
                float4 cs = csum[m];
                float4 xm = single ? make_float4(0.f, 0.f, 0.f, 0.f) : sv;
                float lx = (cs.x - xm.x) * rs - sv.x + PEPS;
                float ly = (cs.y - xm.y) * rs - sv.y + PEPS;
                float lz = (cs.z - xm.z) * rs - sv.z + PEPS;
                float lw = (cs.w - xm.w) * rs - sv.w + PEPS;
                q = fmaf(lx, lx, fmaf(ly, ly, fmaf(lz, lz, fmaf(lw, lw, q))));
                dot = fmaf(sv.x, cs.x, fmaf(sv.y, cs.y, fmaf(sv.z, cs.z, fmaf(sv.w, cs.w, dot))));
            }
            float pos = sqrtf(q);
            float x2 = -2.f * x2sh[ln];
            float ownd2 = x2 + c2s[cnode] - 2.f * (dot / cf);
            float own = sqrtf(fmaxf(ownd2, 0.f));
            float mean_neg = (sums[ln] - own) * (1.f / (float)(NCOMM - 1));
            tmean += fmaxf(pos - mean_neg + ALPHA, 0.f);
            tminv += fmaxf(pos - mins[ln] + ALPHA, 0.f);
        }
    }
    // wave reduction of triplet sums
    #pragma unroll
    for (int msk = 1; msk < 64; msk <<= 1) {
        tmean += __shfl_xor(tmean, msk);
        tminv += __shfl_xor(tminv, msk);
    }
    if (tid == 0) {
        atomicAdd(&accum[0], tmean);
        atomicAdd(&accum[1], tminv);
    }
}

__global__ void k_final(const float* __restrict__ accum, float* __restrict__ out, int N) {
    if (threadIdx.x == 0) {
        out[0] = accum[0] / (float)N;
        out[1] = accum[1] / (float)N;
        out[2] = accum[2] / (float)(NCOMM * DIM);
    }
}

// ---------------- launch ----------------

extern "C" void kernel_launch(void* const* d_in, const int* in_sizes, int n_in,
                              void* d_out, int out_size, void* d_ws, size_t ws_size,
                              hipStream_t stream) {
    const float* NF  = (const float*)d_in[0];
    const int*   CBL = (const int*)d_in[1];
    int N = in_sizes[1] / 2;
    if (N <= 0) return;

    char* ws = (char*)d_ws;
    float* accum   = (float*)ws;                    // 16 B
    int*   counts  = (int*)(ws + 16);               // 2048
    int*   cursor  = (int*)(ws + 16 + 2048);
    int*   offsets = (int*)(ws + 16 + 2 * 2048);
    float* countf  = (float*)(ws + 16 + 3 * 2048);
    float* c2      = (float*)(ws + 16 + 4 * 2048);
    char* p = ws + 16 + 5 * 2048;
    int* comm   = (int*)p; p += (size_t)N * 4;
    int* sorted = (int*)p; p += (size_t)N * 4;
    float* comm_sum = (float*)p; p += (size_t)NCOMM * DIM * 4;
    _Float16* CMh = (_Float16*)p;

    hipMemsetAsync(d_ws, 0, 16 + 2048, stream);     // accum + counts

    int nb = (N + 255) / 256;
    k_prep<<<nb, 256, 0, stream>>>(CBL, comm, counts, N);
    k_scan<<<1, NCOMM, 0, stream>>>(counts, offsets, cursor, countf);
    int nb4 = (N + 1023) / 1024;
    k_sort<<<nb4, 256, 0, stream>>>(comm, cursor, sorted, N);
    k_stats<<<NCOMM, 256, 0, stream>>>(NF, sorted, offsets, counts,
                                       comm_sum, CMh, c2, accum);
    int mb = (N + 127) / 128;
    k_main<<<mb, 64, 0, stream>>>(NF, CMh, comm_sum, c2, countf,
                                  comm, accum, N);
    k_final<<<1, 64, 0, stream>>>(accum, (float*)d_out, N);
}

// Round 20
// 117.855 us; speedup vs baseline: 1.1774x; 1.1774x over previous
//
#include <hip/hip_runtime.h>

#define NCOMM 512
#define DIM   128
#define ALPHA 0.25f
#define PEPS  1e-6f
#define BIGF  1e30f
#define TILE_C 16
#define NT    (NCOMM / TILE_C)   // 32 tiles, 64 half-K substages

typedef __attribute__((ext_vector_type(8))) _Float16 f16x8;
typedef __attribute__((ext_vector_type(4))) float f32x4;

#define GLOAD_LDS16(g, l) __builtin_amdgcn_global_load_lds( \
    (const __attribute__((address_space(1))) void*)(g), \
    (__attribute__((address_space(3))) void*)(l), 16, 0, 0)

// ---------------- prep: comm scatter + histogram (inv eliminated) ----------------
// inv[cbl[i]] = i  =>  comm[cbl[i]] = cbl[N+i] directly; idx0 == identity (algebra).

__global__ void k_prep(const int* __restrict__ cbl, int* __restrict__ comm,
                       int* __restrict__ counts, int N) {
    __shared__ int h[NCOMM];
    int t = threadIdx.x;
    h[t] = 0; h[t + 256] = 0;
    __syncthreads();
    int i = blockIdx.x * 256 + t;
    if (i < N) {
        int p = cbl[i];
        int c = cbl[N + i];
        comm[p] = c;
        atomicAdd(&h[c], 1);
    }
    __syncthreads();
    int v = h[t];        if (v) atomicAdd(&counts[t], v);
    v = h[t + 256];      if (v) atomicAdd(&counts[t + 256], v);
}

__global__ void k_scan(const int* __restrict__ counts, int* __restrict__ offsets,
                       int* __restrict__ cursor, float* __restrict__ countf) {
    __shared__ int sc[NCOMM];
    int t = threadIdx.x;
    int v0 = counts[t];
    sc[t] = v0;
    __syncthreads();
    for (int off = 1; off < NCOMM; off <<= 1) {
        int v = (t >= off) ? sc[t - off] : 0;
        __syncthreads();
        sc[t] += v;
        __syncthreads();
    }
    int excl = sc[t] - v0;
    offsets[t] = excl;
    cursor[t]  = excl;
    countf[t]  = (float)v0;
}

// 1024 elements per block: LDS histogram + one range-reservation atomic per present comm
__global__ void k_sort(const int* __restrict__ comm, int* __restrict__ cursor,
                       int* __restrict__ sorted, int N) {
    __shared__ int h[NCOMM], hb[NCOMM];
    int t = threadIdx.x;
    h[t] = 0; h[t + 256] = 0;
    __syncthreads();
    int j0 = blockIdx.x * 1024 + t;
    int cs[4];
    #pragma unroll
    for (int q = 0; q < 4; ++q) {
        int j = j0 + q * 256;
        cs[q] = (j < N) ? comm[j] : -1;
        if (cs[q] >= 0) atomicAdd(&h[cs[q]], 1);
    }
    __syncthreads();
    int v = h[t];        if (v) hb[t] = atomicAdd(&cursor[t], v);
    v = h[t + 256];      if (v) hb[t + 256] = atomicAdd(&cursor[t + 256], v);
    __syncthreads();
    #pragma unroll
    for (int q = 0; q < 4; ++q) {
        int j = j0 + q * 256;
        if (cs[q] >= 0) {
            int p = atomicAdd(&hb[cs[q]], 1);
            sorted[p] = j;
        }
    }
}

// ---------------- per-community stats: float4 gather, single pass ----------------
// var = (sumsq - cnt*m^2)/(cnt-1): benign cancellation (x~N(0,1), rel err ~1e-6)
// Emits community means as single fp16 (distance error ~5e-5, see k_main note).
// Gather unrolled x4 -> 4 loads in flight per thread.

__global__ void __launch_bounds__(256) k_stats(
        const float* __restrict__ NF,
        const int* __restrict__ sorted, const int* __restrict__ offsets,
        const int* __restrict__ counts,
        float* __restrict__ comm_sum,
        _Float16* __restrict__ CMh,
        float* __restrict__ c2, float* __restrict__ accum) {
    __shared__ int ridx[512];
    __shared__ float4 bufS[256], bufQ[256];
    int c = blockIdx.x, t = threadIdx.x;
    int d4 = t & 31, r = t >> 5;                 // 32 dim-quads x 8 row slots
    int cnt = counts[c], base = offsets[c];
    const float4* NF4 = (const float4*)NF;

    float4 s4 = make_float4(0.f, 0.f, 0.f, 0.f);
    float4 q4 = make_float4(0.f, 0.f, 0.f, 0.f);
    for (int chunk = 0; chunk < cnt; chunk += 512) {
        int m = min(cnt - chunk, 512);
        for (int i = t; i < m; i += 256) ridx[i] = sorted[base + chunk + i];
        __syncthreads();
        int i = r;
        for (; i + 24 < m; i += 32) {
            int a0 = ridx[i], a1 = ridx[i + 8], a2 = ridx[i + 16], a3 = ridx[i + 24];
            float4 v0 = NF4[(size_t)a0 * 32 + d4];
            float4 v1 = NF4[(size_t)a1 * 32 + d4];
            float4 v2 = NF4[(size_t)a2 * 32 + d4];
            float4 v3 = NF4[(size_t)a3 * 32 + d4];
            s4.x += v0.x; s4.y += v0.y; s4.z += v0.z; s4.w += v0.w;
            q4.x = fmaf(v0.x, v0.x, q4.x); q4.y = fmaf(v0.y, v0.y, q4.y);
            q4.z = fmaf(v0.z, v0.z, q4.z); q4.w = fmaf(v0.w, v0.w, q4.w);
            s4.x += v1.x; s4.y += v1.y; s4.z += v1.z; s4.w += v1.w;
            q4.x = fmaf(v1.x, v1.x, q4.x); q4.y = fmaf(v1.y, v1.y, q4.y);
            q4.z = fmaf(v1.z, v1.z, q4.z); q4.w = fmaf(v1.w, v1.w, q4.w);
            s4.x += v2.x; s4.y += v2.y; s4.z += v2.z; s4.w += v2.w;
            q4.x = fmaf(v2.x, v2.x, q4.x); q4.y = fmaf(v2.y, v2.y, q4.y);
            q4.z = fmaf(v2.z, v2.z, q4.z); q4.w = fmaf(v2.w, v2.w, q4.w);
            s4.x += v3.x; s4.y += v3.y; s4.z += v3.z; s4.w += v3.w;
            q4.x = fmaf(v3.x, v3.x, q4.x); q4.y = fmaf(v3.y, v3.y, q4.y);
            q4.z = fmaf(v3.z, v3.z, q4.z); q4.w = fmaf(v3.w, v3.w, q4.w);
        }
        for (; i < m; i += 8) {
            float4 v = NF4[(size_t)ridx[i] * 32 + d4];
            s4.x += v.x; s4.y += v.y; s4.z += v.z; s4.w += v.w;
            q4.x = fmaf(v.x, v.x, q4.x); q4.y = fmaf(v.y, v.y, q4.y);
            q4.z = fmaf(v.z, v.z, q4.z); q4.w = fmaf(v.w, v.w, q4.w);
        }
        __syncthreads();
    }
    bufS[t] = s4; bufQ[t] = q4;
    __syncthreads();
    if (t < 128) {
        float4 a = bufS[t], b = bufS[t + 128];
        a.x += b.x; a.y += b.y; a.z += b.z; a.w += b.w; bufS[t] = a;
        float4 e = bufQ[t], f = bufQ[t + 128];
        e.x += f.x; e.y += f.y; e.z += f.z; e.w += f.w; bufQ[t] = e;
    }
    __syncthreads();
    if (t < 64) {
        float4 a = bufS[t], b = bufS[t + 64];
        a.x += b.x; a.y += b.y; a.z += b.z; a.w += b.w; bufS[t] = a;
        float4 e = bufQ[t], f = bufQ[t + 64];
        e.x += f.x; e.y += f.y; e.z += f.z; e.w += f.w; bufQ[t] = e;
    }
    __syncthreads();
    if (t < 32) {
        float4 a = bufS[t], b = bufS[t + 32];
        a.x += b.x; a.y += b.y; a.z += b.z; a.w += b.w;
        float4 e = bufQ[t], f = bufQ[t + 32];
        e.x += f.x; e.y += f.y; e.z += f.z; e.w += f.w;
        float sarr[4] = {a.x, a.y, a.z, a.w};
        float qarr[4] = {e.x, e.y, e.z, e.w};
        float cf = (float)cnt;
        float mm = 0.f, ee = 0.f;
        #pragma unroll
        for (int k = 0; k < 4; ++k) {
            int d = t * 4 + k;
            float s = sarr[k];
            comm_sum[c * DIM + d] = s;
            float m = (cnt > 0) ? s / cf : 0.f;
            CMh[c * DIM + d] = (_Float16)m;
            float varn = fmaxf(fmaf(-cf * m, m, qarr[k]), 0.f);
            float stdv = sqrtf(varn / fmaxf(cf - 1.f, 1.f));
            float er = stdv - 1.f;
            mm = fmaf(m, m, mm);
            ee = fmaf(er, er, ee);
        }
        #pragma unroll
        for (int msk = 1; msk < 32; msk <<= 1) {
            mm += __shfl_xor(mm, msk);
            ee += __shfl_xor(ee, msk);
        }
        if (t == 0) {
            c2[c] = mm;
            atomicAdd(&accum[2], ee);
        }
    }
}

// ---------------- heavy kernel: MFMA distances + triplet terms ----------------
// SESSION-BEST configuration (r18: 74.7us k_main, 118.5us total). M=64 rows
// per wave, 128-thread blocks (2 waves), grid ceil(N/128). Wave-private
// depth-3 vmcnt(6) pipeline (tails 4/2/0), single-fp16 B (distance err ~5e-5;
// pos/own exact fp32 in LOO), 8 MFMAs per 2 ds_reads per substage. M-sweep
// measured: M=32 -> 78.2us, M=64 -> 74.7us (optimum), M=128 -> 96us (1
// wave/SIMD exposes all latency). No setprio (r12), no sched_barrier (r17:
// neutral), no kernel fusion (r12), no B-stationary (r14/r15).

__global__ void __launch_bounds__(128, 2) k_main(
        const float* __restrict__ NF,
        const _Float16* __restrict__ CMh,
        const float* __restrict__ comm_sum,
        const float* __restrict__ c2g,
        const float* __restrict__ countf,
        const int* __restrict__ comm,
        float* __restrict__ accum, int N) {
    __shared__ _Float16 Bst[2][4][TILE_C * 64];  // [wave][buf] 2 KB each = 16 KB
    __shared__ float c2s[NCOMM];
    __shared__ int   comms[128];
    __shared__ float x2sh[128];    // holds -x^2/2
    __shared__ float sums[128], mins[128];
    __shared__ float red[4];

    int tid = threadIdx.x;         // 0..127
    int w  = tid >> 6;    // wave 0..1
    int l  = tid & 63;
    int lr = l & 15;      // A row within 16-frag / B (comm) col
    int lk = l >> 4;      // k-group
    int n0 = blockIdx.x * 128;

    // per-lane pre-swizzled source offset within a half-tile (16 comms x 64 dims):
    // chunk p = i*64+l -> row = i*8+(l>>3), cp = l&7, swz = cp^(row&7)
    int off0 = ((l >> 3) << 7) + (((l & 7) ^ ((l >> 3) & 7)) << 3);
    const _Float16* gsrc = CMh + off0;
    // substage ss: tile = ss>>1 (16 comms), khalf = ss&1 (64 dims)
    auto stage = [&](int ss, int b) {
        const _Float16* g = gsrc + (size_t)(ss >> 1) * 2048 + (ss & 1) * 64;
        _Float16* lh = &Bst[w][b][0];
        GLOAD_LDS16(g,        lh);
        GLOAD_LDS16(g + 1024, lh + 512);
    };
    stage(0, 0); stage(1, 1); stage(2, 2);   // depth-3 prologue, lands during A conv

    c2s[tid]       = c2g[tid];
    c2s[tid + 128] = c2g[tid + 128];
    c2s[tid + 256] = c2g[tid + 256];
    c2s[tid + 384] = c2g[tid + 384];
    {
        int gn = n0 + tid;
        comms[tid] = (gn < N) ? comm[gn] : -1;
    }

    // ---- A fragments (rows n0 + w*64 + mf*16 + lr), single fp16 + exact fp32 x2
    f16x8 ah[4][4];
    #pragma unroll
    for (int mf = 0; mf < 4; ++mf) {
        int n = n0 + w * 64 + mf * 16 + lr;
        const float4* src = (const float4*)NF + (size_t)n * 32 + lk * 2;
        float p2 = 0.f;
        #pragma unroll
        for (int ks = 0; ks < 4; ++ks) {
            float4 v0 = make_float4(0.f, 0.f, 0.f, 0.f), v1 = v0;
            if (n < N) { v0 = src[ks * 8]; v1 = src[ks * 8 + 1]; }
            float fr[8] = {v0.x, v0.y, v0.z, v0.w, v1.x, v1.y, v1.z, v1.w};
            f16x8 hh;
            #pragma unroll
            for (int t = 0; t < 8; ++t) {
                hh[t] = (_Float16)fr[t];
                p2 = fmaf(fr[t], fr[t], p2);
            }
            ah[mf][ks] = hh;
        }
        p2 += __shfl_xor(p2, 16);
        p2 += __shfl_xor(p2, 32);
        if (lk == 0) x2sh[w * 64 + mf * 16 + lr] = -0.5f * p2;
    }
    __syncthreads();   // drains stage(0..2) + publishes c2s/comms/x2sh

    // per-lane per-row state (C layout: row = lk*4 + j, col = lr)
    f32x4 x2v[4];
    int cnv[4][4];
    float sumv[4][4], minv[4][4];
    #pragma unroll
    for (int mf = 0; mf < 4; ++mf) {
        x2v[mf] = *(const f32x4*)&x2sh[w * 64 + mf * 16 + lk * 4];
        #pragma unroll
        for (int j = 0; j < 4; ++j) {
            cnv[mf][j] = comms[w * 64 + mf * 16 + lk * 4 + j];
            sumv[mf][j] = 0.f; minv[mf][j] = BIGF;
        }
    }

    for (int tt = 0; tt < NT; ++tt) {
        f32x4 acc0, acc1, acc2, acc3;
        // ---- substage kh=0 (ss = 2tt): acc init
        {
            int ssn = 2 * tt + 3;
            if (ssn < 64) stage(ssn, ssn & 3);
            if (tt <= 30) { asm volatile("s_waitcnt vmcnt(6)" ::: "memory"); }
            else          { asm volatile("s_waitcnt vmcnt(2)" ::: "memory"); }
            const _Float16* bp = &Bst[w][(2 * tt) & 3][0];
            acc0 = x2v[0]; acc1 = x2v[1]; acc2 = x2v[2]; acc3 = x2v[3];
            #pragma unroll
            for (int ks2 = 0; ks2 < 2; ++ks2) {
                int ch = (ks2 * 4 + lk) ^ (lr & 7);
                f16x8 b = *(const f16x8*)&bp[(size_t)(lr * 64 + ch * 8)];
                acc0 = __builtin_amdgcn_mfma_f32_16x16x32_f16(ah[0][ks2], b, acc0, 0, 0, 0);
                acc1 = __builtin_amdgcn_mfma_f32_16x16x32_f16(ah[1][ks2], b, acc1, 0, 0, 0);
                acc2 = __builtin_amdgcn_mfma_f32_16x16x32_f16(ah[2][ks2], b, acc2, 0, 0, 0);
                acc3 = __builtin_amdgcn_mfma_f32_16x16x32_f16(ah[3][ks2], b, acc3, 0, 0, 0);
            }
        }
        // ---- substage kh=1 (ss = 2tt+1): accumulate + epilogue
        {
            int ssn = 2 * tt + 4;
            if (ssn < 64) stage(ssn, ssn & 3);
            if (tt <= 29)      { asm volatile("s_waitcnt vmcnt(6)" ::: "memory"); }
            else if (tt == 30) { asm volatile("s_waitcnt vmcnt(4)" ::: "memory"); }
            else               { asm volatile("s_waitcnt vmcnt(0)" ::: "memory"); }
            const _Float16* bp = &Bst[w][(2 * tt + 1) & 3][0];
            #pragma unroll
            for (int ks2 = 0; ks2 < 2; ++ks2) {
                int ch = (ks2 * 4 + lk) ^ (lr & 7);
                f16x8 b = *(const f16x8*)&bp[(size_t)(lr * 64 + ch * 8)];
                acc0 = __builtin_amdgcn_mfma_f32_16x16x32_f16(ah[0][2 + ks2], b, acc0, 0, 0, 0);
                acc1 = __builtin_amdgcn_mfma_f32_16x16x32_f16(ah[1][2 + ks2], b, acc1, 0, 0, 0);
                acc2 = __builtin_amdgcn_mfma_f32_16x16x32_f16(ah[2][2 + ks2], b, acc2, 0, 0, 0);
                acc3 = __builtin_amdgcn_mfma_f32_16x16x32_f16(ah[3][2 + ks2], b, acc3, 0, 0, 0);
            }
            int ccol = tt * TILE_C + lr;
            float c2v = c2s[ccol];
            #pragma unroll
            for (int j = 0; j < 4; ++j) {
                // acc = dot - x^2/2  ->  d^2 = c^2 - 2*acc
                float d2a = fmaf(-2.f, acc0[j], c2v);
                float da  = __builtin_amdgcn_sqrtf(fmaxf(d2a, 0.f));
                sumv[0][j] += da;
                minv[0][j] = fminf(minv[0][j], (cnv[0][j] == ccol) ? BIGF : da);
                float d2b = fmaf(-2.f, acc1[j], c2v);
                float db  = __builtin_amdgcn_sqrtf(fmaxf(d2b, 0.f));
                sumv[1][j] += db;
                minv[1][j] = fminf(minv[1][j], (cnv[1][j] == ccol) ? BIGF : db);
                float d2c = fmaf(-2.f, acc2[j], c2v);
                float dc  = __builtin_amdgcn_sqrtf(fmaxf(d2c, 0.f));
                sumv[2][j] += dc;
                minv[2][j] = fminf(minv[2][j], (cnv[2][j] == ccol) ? BIGF : dc);
                float d2d = fmaf(-2.f, acc3[j], c2v);
                float dd  = __builtin_amdgcn_sqrtf(fmaxf(d2d, 0.f));
                sumv[3][j] += dd;
                minv[3][j] = fminf(minv[3][j], (cnv[3][j] == ccol) ? BIGF : dd);
            }
        }
    }

    // reduce sum/min across the 16 lr lanes sharing each node row
    #pragma unroll
    for (int mf = 0; mf < 4; ++mf)
        #pragma unroll
        for (int j = 0; j < 4; ++j) {
            float sv = sumv[mf][j], mv = minv[mf][j];
            #pragma unroll
            for (int msk = 1; msk < 16; msk <<= 1) {
                sv += __shfl_xor(sv, msk);
                mv = fminf(mv, __shfl_xor(mv, msk));
            }
            if (lr == 0) {
                int idx = w * 64 + mf * 16 + lk * 4 + j;
                sums[idx] = sv; mins[idx] = mv;
            }
        }
    __syncthreads();

    // LOO positive distance + own distance + triplet terms (1 thread per node)
    float tmean = 0.f, tminv = 0.f;
    {
        int ln = tid;
        int n = n0 + ln;
        if (n < N) {
            int cnode = comms[ln];
            float cf  = countf[cnode];
            float cm1 = fmaxf(cf - 1.f, 1.f);
            float rs  = 1.f / cm1;
            bool single = (cf == 1.f);
            const float4* srow = (const float4*)NF + (size_t)n * 32;
            const float4* csum = (const float4*)(comm_sum + (size_t)cnode * DIM);
            float q = 0.f, dot = 0.f;
            #pragma unroll 8
            for (int m = 0; m < 32; ++m) {
                float4 sv = srow[m];
                float4 cs = csum[m];
                float4 xm = single ? make_float4(0.f, 0.f, 0.f, 0.f) : sv;
                float lx = (cs.x - xm.x) * rs - sv.x + PEPS;
                float ly = (cs.y - xm.y) * rs - sv.y + PEPS;
                float lz = (cs.z - xm.z) * rs - sv.z + PEPS;
                float lw = (cs.w - xm.w) * rs - sv.w + PEPS;
                q = fmaf(lx, lx, fmaf(ly, ly, fmaf(lz, lz, fmaf(lw, lw, q))));
                dot = fmaf(sv.x, cs.x, fmaf(sv.y, cs.y, fmaf(sv.z, cs.z, fmaf(sv.w, cs.w, dot))));
            }
            float pos = sqrtf(q);
            float x2 = -2.f * x2sh[ln];
            float ownd2 = x2 + c2s[cnode] - 2.f * (dot / cf);
            float own = sqrtf(fmaxf(ownd2, 0.f));
            float mean_neg = (sums[ln] - own) * (1.f / (float)(NCOMM - 1));
            tmean = fmaxf(pos - mean_neg + ALPHA, 0.f);
            tminv = fmaxf(pos - mins[ln] + ALPHA, 0.f);
        }
    }
    // block reduction of triplet sums
    #pragma unroll
    for (int msk = 1; msk < 64; msk <<= 1) {
        tmean += __shfl_xor(tmean, msk);
        tminv += __shfl_xor(tminv, msk);
    }
    if (l == 0) { red[w * 2] = tmean; red[w * 2 + 1] = tminv; }
    __syncthreads();
    if (tid == 0) {
        atomicAdd(&accum[0], red[0] + red[2]);
        atomicAdd(&accum[1], red[1] + red[3]);
    }
}

__global__ void k_final(const float* __restrict__ accum, float* __restrict__ out, int N) {
    if (threadIdx.x == 0) {
        out[0] = accum[0] / (float)N;
        out[1] = accum[1] / (float)N;
        out[2] = accum[2] / (float)(NCOMM * DIM);
    }
}

// ---------------- launch ----------------

extern "C" void kernel_launch(void* const* d_in, const int* in_sizes, int n_in,
                              void* d_out, int out_size, void* d_ws, size_t ws_size,
                              hipStream_t stream) {
    const float* NF  = (const float*)d_in[0];
    const int*   CBL = (const int*)d_in[1];
    int N = in_sizes[1] / 2;
    if (N <= 0) return;

    char* ws = (char*)d_ws;
    float* accum   = (float*)ws;                    // 16 B
    int*   counts  = (int*)(ws + 16);               // 2048
    int*   cursor  = (int*)(ws + 16 + 2048);
    int*   offsets = (int*)(ws + 16 + 2 * 2048);
    float* countf  = (float*)(ws + 16 + 3 * 2048);
    float* c2      = (float*)(ws + 16 + 4 * 2048);
    char* p = ws + 16 + 5 * 2048;
    int* comm   = (int*)p; p += (size_t)N * 4;
    int* sorted = (int*)p; p += (size_t)N * 4;
    float* comm_sum = (float*)p; p += (size_t)NCOMM * DIM * 4;
    _Float16* CMh = (_Float16*)p;

    hipMemsetAsync(d_ws, 0, 16 + 2048, stream);     // accum + counts

    int nb = (N + 255) / 256;
    k_prep<<<nb, 256, 0, stream>>>(CBL, comm, counts, N);
    k_scan<<<1, NCOMM, 0, stream>>>(counts, offsets, cursor, countf);
    int nb4 = (N + 1023) / 1024;
    k_sort<<<nb4, 256, 0, stream>>>(comm, cursor, sorted, N);
    k_stats<<<NCOMM, 256, 0, stream>>>(NF, sorted, offsets, counts,
                                       comm_sum, CMh, c2, accum);
    int mb = (N + 127) / 128;
    k_main<<<mb, 128, 0, stream>>>(NF, CMh, comm_sum, c2, countf,
                                   comm, accum, N);
    k_final<<<1, 64, 0, stream>>>(accum, (float*)d_out, N);
}